// Round 11
// baseline (672.780 us; speedup 1.0000x reference)
//
#include <hip/hip_runtime.h>
#include <hip/hip_bf16.h>

typedef __hip_bfloat16 bf16;
typedef unsigned int u32;
typedef __attribute__((ext_vector_type(8))) short bf16x8;
typedef __attribute__((ext_vector_type(4))) float f32x4;

#define HWSZ 65536u   // 256*256

__device__ __forceinline__ float b2f_lo(u32 w){ return __uint_as_float(w << 16); }
__device__ __forceinline__ float b2f_hi(u32 w){ return __uint_as_float(w & 0xffff0000u); }
__device__ __forceinline__ float b2f(bf16 v){ return __bfloat162float(v); }
__device__ __forceinline__ bf16 f2b(float v){ return __float2bfloat16(v); }

__device__ __forceinline__ u32 f2bbits(float f){
  u32 x = __float_as_uint(f);
  return ((x + 0x7fffu + ((x >> 16) & 1u)) >> 16) & 0xffffu;  // RNE
}

union ABu { u32 u[4]; bf16x8 v; uint4 q; };

// XOR-swizzled xs index
__device__ __forceinline__ int xsw(int c8, int px){
  return c8 * 192 + ((px & ~7) | ((px ^ c8) & 7));
}

// ---------------- K0: fused conv weights W3[192][576]: W3[o][tap*64+c] = wdw[o,tap]*wq[o,c]
__global__ __launch_bounds__(256) void k0_w3(
    const float* __restrict__ wq, const float* __restrict__ wdw, bf16* __restrict__ w3){
  int idx = blockIdx.x * 256 + threadIdx.x;       // 432*256 = 110592 = 192*576
  int och = idx / 576, r = idx - och * 576;
  int tap = r >> 6, c = r & 63;
  w3[idx] = f2b(wdw[och * 9 + tap] * wq[och * 64 + c]);
}

// ---------------- K12 (v7): pointwise+depthwise as ONE GEMM vs W3, direct tok store.
// 256 threads (4 waves), block = (b, yt 16-row band, xt 8-col strip).
// xs: x bf16 [c8=8][px=180 of 192] 16B units (c8-XOR swizzle). No qs, 1 barrier.
// Wave w owns ch-tile w (16 ch) of each g in {q,k,v}: mt = w + 4*m.
// Output tile n: 128 px = 8 n-tiles; px(n) = row(2*nt + (r16>>3)), col(r16&7).
__global__ __launch_bounds__(256) void k12_fused(
    const float* __restrict__ x, const bf16* __restrict__ w3, bf16* __restrict__ tok){
  __shared__ uint4 xs[8 * 192];                   // 24.0 KB
  int t = threadIdx.x;
  int lane = t & 63, w = t >> 6;                  // 4 waves
  int r16 = lane & 15, g4 = lane >> 4;

  u32 n = blockIdx.x;
  u32 bid = (n & 7u) * 1024u + (n >> 3);          // XCD swizzle (8192 = 8*1024)
  u32 xt = bid & 31u, yt = (bid >> 5) & 15u, b = bid >> 9;
  int y0 = (int)yt * 16, x0 = (int)xt * 8;
  const float* xb = x + (size_t)b * 64 * HWSZ;

  // ---- stage x: 576 units = (c8, rr in [0,18), jq in [0,4)); unit = 2 ch x 10 cols
  for (int u = t; u < 576; u += 256){
    int jq = u & 3, rr = (u >> 2) % 18, c8 = u / 72;
    int yy = y0 - 1 + rr;
    float va[2][10];
    if ((u32)yy < 256u){
      #pragma unroll
      for (int jc = 0; jc < 2; jc++){
        const float* p = xb + (size_t)(c8 * 8 + jq * 2 + jc) * HWSZ + ((size_t)yy << 8);
        float4 A  = *(const float4*)(p + x0);     // 16B-aligned (x0 % 8 == 0)
        float4 Bq = *(const float4*)(p + x0 + 4);
        va[jc][0] = (x0 > 0) ? p[x0 - 1] : 0.f;
        va[jc][1] = A.x;  va[jc][2] = A.y;  va[jc][3] = A.z;  va[jc][4] = A.w;
        va[jc][5] = Bq.x; va[jc][6] = Bq.y; va[jc][7] = Bq.z; va[jc][8] = Bq.w;
        va[jc][9] = (x0 + 8 < 256) ? p[x0 + 8] : 0.f;
      }
    } else {
      #pragma unroll
      for (int jc = 0; jc < 2; jc++)
        #pragma unroll
        for (int e = 0; e < 10; e++) va[jc][e] = 0.f;
    }
    #pragma unroll
    for (int e = 0; e < 10; e++){
      u32 wv = f2bbits(va[0][e]) | (f2bbits(va[1][e]) << 16);
      ((u32*)&xs[xsw(c8, rr * 10 + e)])[jq] = wv;
    }
  }
  __syncthreads();

  // ---- GEMM: D[och=192][px=128] over K=576 (9 taps x 64 ch)
  f32x4 acc[3][8];
  #pragma unroll
  for (int m = 0; m < 3; m++)
    #pragma unroll
    for (int nt = 0; nt < 8; nt++) acc[m][nt] = (f32x4){0.f, 0.f, 0.f, 0.f};

  // W3 row bases for this lane's 3 och rows (och = 64*m + 16*w + r16)
  const bf16* w3r0 = w3 + (size_t)(16 * w + r16) * 576 + g4 * 8;
  const bf16* w3r1 = w3r0 + (size_t)64 * 576;
  const bf16* w3r2 = w3r1 + (size_t)64 * 576;

  int orow = r16 >> 3, ocol = (r16 & 7) + 1;      // output row-in-pair, input col

  #pragma unroll 2
  for (int ks = 0; ks < 18; ks++){
    int tap = ks >> 1;
    int dy = tap / 3, dx = tap % 3;               // 0..2 (input offset = dy, dx directly)
    // A fragments: W3[och][ks*32 + g4*8 .. +7]
    ABu a0, a1, a2;
    a0.q = *(const uint4*)(w3r0 + ks * 32);
    a1.q = *(const uint4*)(w3r1 + ks * 32);
    a2.q = *(const uint4*)(w3r2 + ks * 32);
    int c8 = (ks & 1) * 4 + g4;
    int prow = orow + dy;                         // input row = 2*nt + orow + dy (dy in 0..2)
    int pcol = ocol + dx - 1;                     // input col = (r16&7) + 1 + (dx-1)
    #pragma unroll
    for (int nt = 0; nt < 8; nt++){
      int px = (2 * nt + prow) * 10 + pcol;
      uint4 uq = xs[xsw(c8, px)];
      bf16x8 bv = *reinterpret_cast<bf16x8*>(&uq);
      acc[0][nt] = __builtin_amdgcn_mfma_f32_16x16x32_bf16(a0.v, bv, acc[0][nt], 0, 0, 0);
      acc[1][nt] = __builtin_amdgcn_mfma_f32_16x16x32_bf16(a1.v, bv, acc[1][nt], 0, 0, 0);
      acc[2][nt] = __builtin_amdgcn_mfma_f32_16x16x32_bf16(a2.v, bv, acc[2][nt], 0, 0, 0);
    }
  }

  // ---- store: lane holds 4 ch (och = 64m + 16w + g4*4 + r) of pixel px(nt, r16)
  u32 win = (yt >> 1) * 8u + (xt >> 2);
  int choff = w * 16 + g4 * 4;
  int p1 = (int)(xt & 3u) * 8 + (r16 & 7);
  #pragma unroll
  for (int m = 0; m < 3; m++){
    #pragma unroll
    for (int nt = 0; nt < 8; nt++){
      int row = 2 * nt + orow;
      int h = (int)(yt & 1u) * 4 + (row >> 2);
      int p0r = row & 3;
      size_t off = (((((size_t)m * 16 + b) * 8 + h) * 64 + win) * 8192)
                 + (size_t)p0r * 2048 + (size_t)p1 * 64 + choff;
      u32 lo = f2bbits(acc[m][nt][0]) | (f2bbits(acc[m][nt][1]) << 16);
      u32 hi = f2bbits(acc[m][nt][2]) | (f2bbits(acc[m][nt][3]) << 16);
      *(uint2*)(tok + off) = make_uint2(lo, hi);
    }
  }
}

// ---------------- K3 (MFMA): sim partials over d-quarter -> sim4[part][b][h][64][64]
__global__ __launch_bounds__(256) void k3_sim(
    const bf16* __restrict__ tok, float* __restrict__ sim4){
  __shared__ short qs[64 * 72];
  __shared__ short ks[64 * 72];
  int t = threadIdx.x;
  int lane = t & 63, w = t >> 6;
  int r16 = lane & 15, g4 = lane >> 4;
  u32 bid = blockIdx.x;
  u32 part = bid & 3u, h = (bid >> 2) & 7u, b = bid >> 5;
  const bf16* qb = tok + ((size_t)(((0 * 16 + b) * 8 + h) * 64)) * 8192 + part * 2048;
  const bf16* kb = tok + ((size_t)(((1 * 16 + b) * 8 + h) * 64)) * 8192 + part * 2048;

  int stok = t >> 2, soct = t & 3;

  f32x4 acc[4];
  #pragma unroll
  for (int jt = 0; jt < 4; jt++) acc[jt] = (f32x4){0.f,0.f,0.f,0.f};

  for (int s = 0; s < 32; s++){
    int d0 = s * 64;
    __syncthreads();
    {
      uint4 q0 = *(const uint4*)(qb + (size_t)stok * 8192 + d0 + soct * 8);
      uint4 q1 = *(const uint4*)(qb + (size_t)stok * 8192 + d0 + soct * 8 + 32);
      uint4 k0 = *(const uint4*)(kb + (size_t)stok * 8192 + d0 + soct * 8);
      uint4 k1 = *(const uint4*)(kb + (size_t)stok * 8192 + d0 + soct * 8 + 32);
      *(uint4*)&qs[stok * 72 + soct * 8]      = q0;
      *(uint4*)&qs[stok * 72 + soct * 8 + 32] = q1;
      *(uint4*)&ks[stok * 72 + soct * 8]      = k0;
      *(uint4*)&ks[stok * 72 + soct * 8 + 32] = k1;
    }
    __syncthreads();
    #pragma unroll
    for (int kt = 0; kt < 2; kt++){
      bf16x8 a = *(const bf16x8*)&qs[(w * 16 + r16) * 72 + kt * 32 + g4 * 8];
      #pragma unroll
      for (int jt = 0; jt < 4; jt++){
        bf16x8 bb = *(const bf16x8*)&ks[(jt * 16 + r16) * 72 + kt * 32 + g4 * 8];
        acc[jt] = __builtin_amdgcn_mfma_f32_16x16x32_bf16(a, bb, acc[jt], 0, 0, 0);
      }
    }
  }

  float* sp = sim4 + ((((size_t)part * 16 + b) * 8 + h) * 64) * 64;
  #pragma unroll
  for (int jt = 0; jt < 4; jt++)
    #pragma unroll
    for (int r = 0; r < 4; r++)
      sp[(w * 16 + g4 * 4 + r) * 64 + jt * 16 + r16] = acc[jt][r];
}

// ---------------- K4: combine partials, scale, +pos_emb, softmax
__global__ __launch_bounds__(64) void k4_softmax(
    const float* __restrict__ sim4, const float* __restrict__ pos, float* __restrict__ attn){
  int j = threadIdx.x;
  u32 bid = blockIdx.x;
  u32 i = bid & 63u, h = (bid >> 6) & 7u, b = bid >> 9;
  size_t o = (((size_t)b * 8 + h) * 64 + i) * 64 + j;
  const size_t pstride = (size_t)16 * 8 * 64 * 64;
  float s = sim4[o] + sim4[o + pstride] + sim4[o + 2 * pstride] + sim4[o + 3 * pstride];
  s = s * 0.011048543456039806f + pos[(((size_t)h * 64) + i) * 64 + j];
  float m = s;
  #pragma unroll
  for (int off = 32; off; off >>= 1) m = fmaxf(m, __shfl_xor(m, off));
  float e = __expf(s - m);
  float sum = e;
  #pragma unroll
  for (int off = 32; off; off >>= 1) sum += __shfl_xor(sum, off);
  attn[o] = e / sum;
}

// ---------------- K5 (MFMA): otok[i,d] = sum_j attn[i,j] * V[j,d]
__global__ __launch_bounds__(256) void k5_av(
    const bf16* __restrict__ tok, const float* __restrict__ attn, bf16* __restrict__ otok){
  __shared__ short vt[4][64 * 72];
  int t = threadIdx.x;
  int lane = t & 63, w = t >> 6;
  int r16 = lane & 15, g4 = lane >> 4;
  u32 bid = blockIdx.x;
  u32 q = bid & 3u, h = (bid >> 2) & 7u, b = bid >> 5;
  const bf16* vb = tok + ((size_t)(((2 * 16 + b) * 8 + h) * 64)) * 8192;
  const float* ab = attn + (((size_t)b * 8 + h) * 64) * 64;
  bf16* ob = otok + (((size_t)b * 8 + h) * 64) * 8192;

  bf16x8 af[4][2];
  #pragma unroll
  for (int it = 0; it < 4; it++)
    #pragma unroll
    for (int kt = 0; kt < 2; kt++){
      const float* ar = ab + (it * 16 + r16) * 64 + kt * 32 + g4 * 8;
      ABu pk;
      #pragma unroll
      for (int j = 0; j < 4; j++)
        pk.u[j] = f2bbits(ar[2 * j]) | (f2bbits(ar[2 * j + 1]) << 16);
      af[it][kt] = pk.v;
    }

  short* vtw = vt[w];
  for (int s = 0; s < 8; s++){
    int d0 = (int)q * 2048 + s * 256 + w * 64;
    uint4 ld[8];
    const bf16* vp = vb + (size_t)lane * 8192 + d0;
    #pragma unroll
    for (int u = 0; u < 8; u++) ld[u] = *(const uint4*)(vp + u * 8);
    #pragma unroll
    for (int u = 0; u < 8; u++){
      const u32* wd = (const u32*)&ld[u];
      #pragma unroll
      for (int e = 0; e < 4; e++){
        int d = u * 8 + e * 2;
        vtw[d * 72 + lane]       = (short)(wd[e] & 0xffffu);
        vtw[(d + 1) * 72 + lane] = (short)(wd[e] >> 16);
      }
    }
    #pragma unroll
    for (int dt = 0; dt < 4; dt++){
      bf16x8 b0 = *(const bf16x8*)&vtw[(dt * 16 + r16) * 72 + 0 * 32 + g4 * 8];
      bf16x8 b1 = *(const bf16x8*)&vtw[(dt * 16 + r16) * 72 + 1 * 32 + g4 * 8];
      #pragma unroll
      for (int it = 0; it < 4; it++){
        f32x4 acc = (f32x4){0.f,0.f,0.f,0.f};
        acc = __builtin_amdgcn_mfma_f32_16x16x32_bf16(af[it][0], b0, acc, 0, 0, 0);
        acc = __builtin_amdgcn_mfma_f32_16x16x32_bf16(af[it][1], b1, acc, 0, 0, 0);
        #pragma unroll
        for (int r = 0; r < 4; r++)
          ob[(size_t)(it * 16 + g4 * 4 + r) * 8192 + d0 + dt * 16 + r16] = f2b(acc[r]);
      }
    }
  }
}

// ---------------- K6 (MFMA): out[b,64,HW] fp32 = Wp[64,64] x OT[64,HW] + bias
__global__ __launch_bounds__(256) void k6_mfma(
    const bf16* __restrict__ otok, const float* __restrict__ wp,
    const float* __restrict__ bp, float* __restrict__ out){
  __shared__ uint4 xs[1024];
  int t = threadIdx.x;
  int lane = t & 63, w = t >> 6;
  u32 pix0 = blockIdx.x * 128u;
  u32 b = pix0 >> 16, hw0 = pix0 & 65535u;
  int y = (int)(hw0 >> 8);
  int p0 = y & 31, h = p0 >> 2, prow = (p0 & 3) * 2048;
  int iy = (y >> 5) << 3;

  {
    int pix = t & 127, half = t >> 7;
    int xx = (int)(hw0 & 255u) + pix;
    int i = iy + (xx >> 5), p1 = xx & 31;
    const bf16* ip = otok + ((((size_t)b * 8 + h) * 64 + i)) * 8192 + prow + p1 * 64;
    #pragma unroll
    for (int g = 0; g < 4; g++){
      int c8 = half * 4 + g;
      xs[c8 * 128 + pix] = *(const uint4*)(ip + c8 * 8);
    }
  }

  int r16 = lane & 15, g4 = lane >> 4;
  bf16x8 af[2];
  int och = w * 16 + r16;
  #pragma unroll
  for (int kt = 0; kt < 2; kt++){
    const float* wr = wp + och * 64 + kt * 32 + g4 * 8;
    ABu pk;
    #pragma unroll
    for (int j = 0; j < 4; j++)
      pk.u[j] = f2bbits(wr[2 * j]) | (f2bbits(wr[2 * j + 1]) << 16);
    af[kt] = pk.v;
  }
  float bias[4];
  #pragma unroll
  for (int r = 0; r < 4; r++) bias[r] = bp[w * 16 + g4 * 4 + r];
  __syncthreads();

  f32x4 acc[8];
  #pragma unroll
  for (int pt = 0; pt < 8; pt++) acc[pt] = (f32x4){bias[0], bias[1], bias[2], bias[3]};

  #pragma unroll
  for (int pt = 0; pt < 8; pt++){
    uint4 u0 = xs[(0 * 4 + g4) * 128 + pt * 16 + r16];
    uint4 u1 = xs[(1 * 4 + g4) * 128 + pt * 16 + r16];
    bf16x8 b0 = *reinterpret_cast<bf16x8*>(&u0);
    bf16x8 b1 = *reinterpret_cast<bf16x8*>(&u1);
    acc[pt] = __builtin_amdgcn_mfma_f32_16x16x32_bf16(af[0], b0, acc[pt], 0, 0, 0);
    acc[pt] = __builtin_amdgcn_mfma_f32_16x16x32_bf16(af[1], b1, acc[pt], 0, 0, 0);
  }

  float* op = out + (size_t)b * 64 * HWSZ + hw0;
  int ochb = w * 16 + g4 * 4;
  #pragma unroll
  for (int pt = 0; pt < 8; pt++)
    #pragma unroll
    for (int r = 0; r < 4; r++)
      op[(size_t)(ochb + r) * HWSZ + pt * 16 + r16] = acc[pt][r];
}

extern "C" void kernel_launch(void* const* d_in, const int* in_sizes, int n_in,
                              void* d_out, int out_size, void* d_ws, size_t ws_size,
                              hipStream_t stream){
  const float* x   = (const float*)d_in[0];
  const float* wq  = (const float*)d_in[1];
  const float* wdw = (const float*)d_in[2];
  const float* wp  = (const float*)d_in[3];
  const float* bp  = (const float*)d_in[4];
  const float* pos = (const float*)d_in[5];
  float* out = (float*)d_out;
  (void)in_sizes; (void)n_in; (void)out_size; (void)ws_size;

  char* ws = (char*)d_ws;
  bf16*  tok  = (bf16*)(ws + 402653184u);
  bf16*  otok = (bf16*)ws;
  float* sim4 = (float*)(ws + 134217728u);
  float* attn = (float*)(ws + 142606336u);
  bf16*  w3   = (bf16*)(ws + 144703488u);   // 221,184 B, before tok region

  k0_w3<<<dim3(432), dim3(256), 0, stream>>>(wq, wdw, w3);
  k12_fused<<<dim3(8192), dim3(256), 0, stream>>>(x, w3, tok);
  k3_sim<<<dim3(512),   dim3(256), 0, stream>>>(tok, sim4);
  k4_softmax<<<dim3(8192), dim3(64), 0, stream>>>(sim4, pos, attn);
  k5_av<<<dim3(512),  dim3(256), 0, stream>>>(tok, attn, otok);
  k6_mfma<<<dim3(8192), dim3(256), 0, stream>>>(otok, wp, bp, out);
}

// Round 12
// 565.691 us; speedup vs baseline: 1.1893x; 1.1893x over previous
//
#include <hip/hip_runtime.h>
#include <hip/hip_bf16.h>

typedef __hip_bfloat16 bf16;
typedef unsigned int u32;
typedef __attribute__((ext_vector_type(8))) short bf16x8;
typedef __attribute__((ext_vector_type(4))) float f32x4;

#define HWSZ 65536u   // 256*256

__device__ __forceinline__ float b2f_lo(u32 w){ return __uint_as_float(w << 16); }
__device__ __forceinline__ float b2f_hi(u32 w){ return __uint_as_float(w & 0xffff0000u); }
__device__ __forceinline__ float b2f(bf16 v){ return __bfloat162float(v); }
__device__ __forceinline__ bf16 f2b(float v){ return __float2bfloat16(v); }

__device__ __forceinline__ u32 f2bbits(float f){
  u32 x = __float_as_uint(f);
  return ((x + 0x7fffu + ((x >> 16) & 1u)) >> 16) & 0xffffu;  // RNE
}

union ABu { u32 u[4]; bf16x8 v; uint4 q; };

// XOR-swizzled xs index. Slot mixes px low bits, px>>3 AND c8 so that
// (a) MFMA b128 reads stay balanced (<=2-way per c8-group),
// (b) staging u32 writes (lanes differ by px+=40) land on distinct banks.
__device__ __forceinline__ int xsw(int c8, int px){
  return c8 * 192 + ((px & ~7) | ((px ^ (px >> 3) ^ c8) & 7));
}

// ---------------- K12 (fused, r6 structure + fixed swizzle): pointwise qkv (MFMA)
// + 3x3 depthwise + tokenize. 256 threads (4 waves), block = (b, yt, xt).
// px region = 18 rows x 10 cols = 180, padded to 192.
__global__ __launch_bounds__(256) void k12_fused(
    const float* __restrict__ x, const float* __restrict__ wq,
    const float* __restrict__ wdw, bf16* __restrict__ tok){
  __shared__ uint4 xs[8 * 192];              // 24.0 KB
  __shared__ unsigned short qs[192 * 68];    // 25.5 KB
  int t = threadIdx.x;
  int lane = t & 63, w = t >> 6;
  int r16 = lane & 15, g4 = lane >> 4;

  u32 n = blockIdx.x;
  u32 bid = (n & 7u) * 1024u + (n >> 3);     // XCD swizzle (8192 = 8*1024, bijective)
  u32 xt = bid & 31u, yt = (bid >> 5) & 15u, b = bid >> 9;
  int y0 = (int)yt * 16, x0 = (int)xt * 8;

  const float* xb = x + (size_t)b * 64 * HWSZ;

  // ---- stage x: 288 units = (c8, rr in [0,18), jh in {0,1}); unit = 4 ch x 10 cols
  for (int u = t; u < 288; u += 256){
    int jh = u & 1, rr = (u >> 1) % 18, c8 = u / 36;
    int yy = y0 - 1 + rr;
    float va[4][10];
    if ((u32)yy < 256u){
      #pragma unroll
      for (int jc = 0; jc < 4; jc++){
        const float* p = xb + (size_t)(c8 * 8 + jh * 4 + jc) * HWSZ + ((size_t)yy << 8);
        float4 A  = *(const float4*)(p + x0);        // 16B-aligned (x0 % 8 == 0)
        float4 Bq = *(const float4*)(p + x0 + 4);
        va[jc][0] = (x0 > 0) ? p[x0 - 1] : 0.f;
        va[jc][1] = A.x;  va[jc][2] = A.y;  va[jc][3] = A.z;  va[jc][4] = A.w;
        va[jc][5] = Bq.x; va[jc][6] = Bq.y; va[jc][7] = Bq.z; va[jc][8] = Bq.w;
        va[jc][9] = (x0 + 8 < 256) ? p[x0 + 8] : 0.f;
      }
    } else {
      #pragma unroll
      for (int jc = 0; jc < 4; jc++)
        #pragma unroll
        for (int e = 0; e < 10; e++) va[jc][e] = 0.f;
    }
    #pragma unroll
    for (int e = 0; e < 10; e++){
      u32 w0 = f2bbits(va[0][e]) | (f2bbits(va[1][e]) << 16);
      u32 w1 = f2bbits(va[2][e]) | (f2bbits(va[3][e]) << 16);
      ((uint2*)&xs[xsw(c8, rr * 10 + e)])[jh] = make_uint2(w0, w1);
    }
  }
  if (t < 96){                                        // zero-pad px 180..191
    int c8 = t / 12, px = 180 + (t % 12);
    xs[xsw(c8, px)] = make_uint4(0u, 0u, 0u, 0u);
  }

  int cth = t & 63, rq = w;                           // dwconv decomposition
  int h = (int)(yt & 1u) * 4 + rq;
  u32 win = (yt >> 1) * 8u + (xt >> 2);

  for (int g = 0; g < 3; g++){
    __syncthreads();                                  // xs ready / qs free
    // ---- pointwise MFMA: wave w owns och-tile w (16 rows of 64), 12 n-tiles
    bf16x8 af[2];
    {
      int och = g * 64 + w * 16 + r16;
      #pragma unroll
      for (int kt = 0; kt < 2; kt++){
        const float* wr = wq + och * 64 + kt * 32 + g4 * 8;
        ABu pk;
        #pragma unroll
        for (int j = 0; j < 4; j++)
          pk.u[j] = f2bbits(wr[2 * j]) | (f2bbits(wr[2 * j + 1]) << 16);
        af[kt] = pk.v;
      }
    }
    #pragma unroll
    for (int nt = 0; nt < 12; nt++){
      f32x4 acc = (f32x4){0.f, 0.f, 0.f, 0.f};
      #pragma unroll
      for (int kt = 0; kt < 2; kt++){
        uint4 uq = xs[xsw(kt * 4 + g4, nt * 16 + r16)];
        acc = __builtin_amdgcn_mfma_f32_16x16x32_bf16(
            af[kt], *reinterpret_cast<bf16x8*>(&uq), acc, 0, 0, 0);
      }
      int px = nt * 16 + r16;
      u32 lo = f2bbits(acc[0]) | (f2bbits(acc[1]) << 16);
      u32 hi = f2bbits(acc[2]) | (f2bbits(acc[3]) << 16);
      *(uint2*)&qs[px * 68 + w * 16 + g4 * 4] = make_uint2(lo, hi);
    }
    __syncthreads();                                  // qs ready

    // ---- depthwise 3x3 + tokenized store: thread = (cth, row-quad rq)
    const float* wg = wdw + ((size_t)g * 64 + cth) * 9;
    float d0=wg[0],d1=wg[1],d2=wg[2],d3=wg[3],d4=wg[4],d5=wg[5],d6=wg[6],d7=wg[7],d8=wg[8];
    bf16* op = tok + (((((size_t)g * 16 + b) * 8 + h) * 64 + win) * 8192)
             + (size_t)(xt & 3u) * 512 + cth;
    float rbf[3][10];
    #define QLD(s, R) do{ _Pragma("unroll") for (int _cr = 0; _cr < 10; _cr++) \
      rbf[s][_cr] = __uint_as_float(((u32)qs[((R) * 10 + _cr) * 68 + cth]) << 16); }while(0)
    QLD(0, rq * 4 + 0);
    QLD(1, rq * 4 + 1);
    QLD(2, rq * 4 + 2);
    #pragma unroll
    for (int rr2 = 0; rr2 < 4; rr2++){
      const int sT = rr2 % 3, sM = (rr2 + 1) % 3, sB = (rr2 + 2) % 3;
      #pragma unroll
      for (int co = 0; co < 8; co++){
        float o = rbf[sT][co]*d0 + rbf[sT][co+1]*d1 + rbf[sT][co+2]*d2
                + rbf[sM][co]*d3 + rbf[sM][co+1]*d4 + rbf[sM][co+2]*d5
                + rbf[sB][co]*d6 + rbf[sB][co+1]*d7 + rbf[sB][co+2]*d8;
        op[(size_t)rr2 * 2048 + co * 64] = f2b(o);
      }
      if (rr2 < 3) QLD(sT, rq * 4 + rr2 + 3);
    }
    #undef QLD
  }
}

// ---------------- K3 (MFMA): sim partials over d-quarter -> sim4[part][b][h][64][64]
__global__ __launch_bounds__(256) void k3_sim(
    const bf16* __restrict__ tok, float* __restrict__ sim4){
  __shared__ short qs[64 * 72];
  __shared__ short ks[64 * 72];
  int t = threadIdx.x;
  int lane = t & 63, w = t >> 6;
  int r16 = lane & 15, g4 = lane >> 4;
  u32 bid = blockIdx.x;
  u32 part = bid & 3u, h = (bid >> 2) & 7u, b = bid >> 5;
  const bf16* qb = tok + ((size_t)(((0 * 16 + b) * 8 + h) * 64)) * 8192 + part * 2048;
  const bf16* kb = tok + ((size_t)(((1 * 16 + b) * 8 + h) * 64)) * 8192 + part * 2048;

  int stok = t >> 2, soct = t & 3;

  f32x4 acc[4];
  #pragma unroll
  for (int jt = 0; jt < 4; jt++) acc[jt] = (f32x4){0.f,0.f,0.f,0.f};

  for (int s = 0; s < 32; s++){
    int d0 = s * 64;
    __syncthreads();
    {
      uint4 q0 = *(const uint4*)(qb + (size_t)stok * 8192 + d0 + soct * 8);
      uint4 q1 = *(const uint4*)(qb + (size_t)stok * 8192 + d0 + soct * 8 + 32);
      uint4 k0 = *(const uint4*)(kb + (size_t)stok * 8192 + d0 + soct * 8);
      uint4 k1 = *(const uint4*)(kb + (size_t)stok * 8192 + d0 + soct * 8 + 32);
      *(uint4*)&qs[stok * 72 + soct * 8]      = q0;
      *(uint4*)&qs[stok * 72 + soct * 8 + 32] = q1;
      *(uint4*)&ks[stok * 72 + soct * 8]      = k0;
      *(uint4*)&ks[stok * 72 + soct * 8 + 32] = k1;
    }
    __syncthreads();
    #pragma unroll
    for (int kt = 0; kt < 2; kt++){
      bf16x8 a = *(const bf16x8*)&qs[(w * 16 + r16) * 72 + kt * 32 + g4 * 8];
      #pragma unroll
      for (int jt = 0; jt < 4; jt++){
        bf16x8 bb = *(const bf16x8*)&ks[(jt * 16 + r16) * 72 + kt * 32 + g4 * 8];
        acc[jt] = __builtin_amdgcn_mfma_f32_16x16x32_bf16(a, bb, acc[jt], 0, 0, 0);
      }
    }
  }

  float* sp = sim4 + ((((size_t)part * 16 + b) * 8 + h) * 64) * 64;
  #pragma unroll
  for (int jt = 0; jt < 4; jt++)
    #pragma unroll
    for (int r = 0; r < 4; r++)
      sp[(w * 16 + g4 * 4 + r) * 64 + jt * 16 + r16] = acc[jt][r];
}

// ---------------- K5 (MFMA, fused softmax): combine sim4 partials + pos, softmax,
// then otok[i,d] = sum_j attn[i,j] * V[j,d]. k4 eliminated.
__global__ __launch_bounds__(256) void k5_av(
    const bf16* __restrict__ tok, const float* __restrict__ sim4,
    const float* __restrict__ pos, bf16* __restrict__ otok){
  __shared__ short vt[4][64 * 72];
  int t = threadIdx.x;
  int lane = t & 63, w = t >> 6;
  int r16 = lane & 15, g4 = lane >> 4;
  u32 bid = blockIdx.x;
  u32 q = bid & 3u, h = (bid >> 2) & 7u, b = bid >> 5;
  const bf16* vb = tok + ((size_t)(((2 * 16 + b) * 8 + h) * 64)) * 8192;
  bf16* ob = otok + (((size_t)b * 8 + h) * 64) * 8192;

  // ---- fused softmax -> attn fragments (bf16)
  // Row i = it*16+r16 lives in the 4 lanes {r16 + 16*g4}; full-row reduce via
  // shfl_xor(16) + shfl_xor(32).
  const float* s0 = sim4 + (((size_t)b * 8 + h) * 64) * 64;
  const size_t pstr = (size_t)16 * 8 * 64 * 64;
  const float* pb = pos + ((size_t)h * 64) * 64;
  const float SC = 0.011048543456039806f;

  bf16x8 af[4][2];
  #pragma unroll
  for (int it = 0; it < 4; it++){
    int row = it * 16 + r16;
    const float* rp = s0 + (size_t)row * 64;
    float ev[2][8];
    #pragma unroll
    for (int kt = 0; kt < 2; kt++){
      int jb = kt * 32 + g4 * 8;
      #pragma unroll
      for (int hq = 0; hq < 2; hq++){
        float4 a0 = *(const float4*)(rp + jb + hq * 4);
        float4 a1 = *(const float4*)(rp + pstr + jb + hq * 4);
        float4 a2 = *(const float4*)(rp + 2 * pstr + jb + hq * 4);
        float4 a3 = *(const float4*)(rp + 3 * pstr + jb + hq * 4);
        float4 pe = *(const float4*)(pb + (size_t)row * 64 + jb + hq * 4);
        ev[kt][hq * 4 + 0] = (a0.x + a1.x + a2.x + a3.x) * SC + pe.x;
        ev[kt][hq * 4 + 1] = (a0.y + a1.y + a2.y + a3.y) * SC + pe.y;
        ev[kt][hq * 4 + 2] = (a0.z + a1.z + a2.z + a3.z) * SC + pe.z;
        ev[kt][hq * 4 + 3] = (a0.w + a1.w + a2.w + a3.w) * SC + pe.w;
      }
    }
    float m = ev[0][0];
    #pragma unroll
    for (int kt = 0; kt < 2; kt++)
      #pragma unroll
      for (int j = 0; j < 8; j++) m = fmaxf(m, ev[kt][j]);
    m = fmaxf(m, __shfl_xor(m, 16));
    m = fmaxf(m, __shfl_xor(m, 32));
    float sum = 0.f;
    #pragma unroll
    for (int kt = 0; kt < 2; kt++)
      #pragma unroll
      for (int j = 0; j < 8; j++){ ev[kt][j] = __expf(ev[kt][j] - m); sum += ev[kt][j]; }
    sum += __shfl_xor(sum, 16);
    sum += __shfl_xor(sum, 32);
    float inv = 1.f / sum;
    #pragma unroll
    for (int kt = 0; kt < 2; kt++){
      ABu pk;
      #pragma unroll
      for (int j = 0; j < 4; j++)
        pk.u[j] = f2bbits(ev[kt][2 * j] * inv) | (f2bbits(ev[kt][2 * j + 1] * inv) << 16);
      af[it][kt] = pk.v;
    }
  }

  // ---- P @ V
  short* vtw = vt[w];
  for (int s = 0; s < 8; s++){
    int d0 = (int)q * 2048 + s * 256 + w * 64;
    uint4 ld[8];
    const bf16* vp = vb + (size_t)lane * 8192 + d0;
    #pragma unroll
    for (int u = 0; u < 8; u++) ld[u] = *(const uint4*)(vp + u * 8);
    #pragma unroll
    for (int u = 0; u < 8; u++){
      const u32* wd = (const u32*)&ld[u];
      #pragma unroll
      for (int e = 0; e < 4; e++){
        int d = u * 8 + e * 2;
        vtw[d * 72 + lane]       = (short)(wd[e] & 0xffffu);
        vtw[(d + 1) * 72 + lane] = (short)(wd[e] >> 16);
      }
    }
    #pragma unroll
    for (int dt = 0; dt < 4; dt++){
      bf16x8 b0 = *(const bf16x8*)&vtw[(dt * 16 + r16) * 72 + 0 * 32 + g4 * 8];
      bf16x8 b1 = *(const bf16x8*)&vtw[(dt * 16 + r16) * 72 + 1 * 32 + g4 * 8];
      #pragma unroll
      for (int it = 0; it < 4; it++){
        f32x4 acc = (f32x4){0.f,0.f,0.f,0.f};
        acc = __builtin_amdgcn_mfma_f32_16x16x32_bf16(af[it][0], b0, acc, 0, 0, 0);
        acc = __builtin_amdgcn_mfma_f32_16x16x32_bf16(af[it][1], b1, acc, 0, 0, 0);
        #pragma unroll
        for (int r = 0; r < 4; r++)
          ob[(size_t)(it * 16 + g4 * 4 + r) * 8192 + d0 + dt * 16 + r16] = f2b(acc[r]);
      }
    }
  }
}

// ---------------- K6 (MFMA): out[b,64,HW] fp32 = Wp[64,64] x OT[64,HW] + bias
__global__ __launch_bounds__(256) void k6_mfma(
    const bf16* __restrict__ otok, const float* __restrict__ wp,
    const float* __restrict__ bp, float* __restrict__ out){
  __shared__ uint4 xs[1024];
  int t = threadIdx.x;
  int lane = t & 63, w = t >> 6;
  u32 pix0 = blockIdx.x * 128u;
  u32 b = pix0 >> 16, hw0 = pix0 & 65535u;
  int y = (int)(hw0 >> 8);
  int p0 = y & 31, h = p0 >> 2, prow = (p0 & 3) * 2048;
  int iy = (y >> 5) << 3;

  {
    int pix = t & 127, half = t >> 7;
    int xx = (int)(hw0 & 255u) + pix;
    int i = iy + (xx >> 5), p1 = xx & 31;
    const bf16* ip = otok + ((((size_t)b * 8 + h) * 64 + i)) * 8192 + prow + p1 * 64;
    #pragma unroll
    for (int g = 0; g < 4; g++){
      int c8 = half * 4 + g;
      xs[c8 * 128 + pix] = *(const uint4*)(ip + c8 * 8);
    }
  }

  int r16 = lane & 15, g4 = lane >> 4;
  bf16x8 af[2];
  int och = w * 16 + r16;
  #pragma unroll
  for (int kt = 0; kt < 2; kt++){
    const float* wr = wp + och * 64 + kt * 32 + g4 * 8;
    ABu pk;
    #pragma unroll
    for (int j = 0; j < 4; j++)
      pk.u[j] = f2bbits(wr[2 * j]) | (f2bbits(wr[2 * j + 1]) << 16);
    af[kt] = pk.v;
  }
  float bias[4];
  #pragma unroll
  for (int r = 0; r < 4; r++) bias[r] = bp[w * 16 + g4 * 4 + r];
  __syncthreads();

  f32x4 acc[8];
  #pragma unroll
  for (int pt = 0; pt < 8; pt++) acc[pt] = (f32x4){bias[0], bias[1], bias[2], bias[3]};

  #pragma unroll
  for (int pt = 0; pt < 8; pt++){
    uint4 u0 = xs[(0 * 4 + g4) * 128 + pt * 16 + r16];
    uint4 u1 = xs[(1 * 4 + g4) * 128 + pt * 16 + r16];
    bf16x8 b0 = *reinterpret_cast<bf16x8*>(&u0);
    bf16x8 b1 = *reinterpret_cast<bf16x8*>(&u1);
    acc[pt] = __builtin_amdgcn_mfma_f32_16x16x32_bf16(af[0], b0, acc[pt], 0, 0, 0);
    acc[pt] = __builtin_amdgcn_mfma_f32_16x16x32_bf16(af[1], b1, acc[pt], 0, 0, 0);
  }

  float* op = out + (size_t)b * 64 * HWSZ + hw0;
  int ochb = w * 16 + g4 * 4;
  #pragma unroll
  for (int pt = 0; pt < 8; pt++)
    #pragma unroll
    for (int r = 0; r < 4; r++)
      op[(size_t)(ochb + r) * HWSZ + pt * 16 + r16] = acc[pt][r];
}

extern "C" void kernel_launch(void* const* d_in, const int* in_sizes, int n_in,
                              void* d_out, int out_size, void* d_ws, size_t ws_size,
                              hipStream_t stream){
  const float* x   = (const float*)d_in[0];
  const float* wq  = (const float*)d_in[1];
  const float* wdw = (const float*)d_in[2];
  const float* wp  = (const float*)d_in[3];
  const float* bp  = (const float*)d_in[4];
  const float* pos = (const float*)d_in[5];
  float* out = (float*)d_out;
  (void)in_sizes; (void)n_in; (void)out_size; (void)ws_size;

  char* ws = (char*)d_ws;
  bf16*  tok  = (bf16*)(ws + 402653184u);
  bf16*  otok = (bf16*)ws;
  float* sim4 = (float*)(ws + 134217728u);

  k12_fused<<<dim3(8192), dim3(256), 0, stream>>>(x, wq, wdw, tok);
  k3_sim<<<dim3(512),   dim3(256), 0, stream>>>(tok, sim4);
  k5_av<<<dim3(512),  dim3(256), 0, stream>>>(tok, sim4, pos, otok);
  k6_mfma<<<dim3(8192), dim3(256), 0, stream>>>(otok, wp, bp, out);
}

// Round 13
// 554.503 us; speedup vs baseline: 1.2133x; 1.0202x over previous
//
#include <hip/hip_runtime.h>
#include <hip/hip_bf16.h>

typedef __hip_bfloat16 bf16;
typedef unsigned int u32;
typedef __attribute__((ext_vector_type(8))) short bf16x8;
typedef __attribute__((ext_vector_type(4))) float f32x4;

#define HWSZ 65536u   // 256*256

__device__ __forceinline__ float b2f_lo(u32 w){ return __uint_as_float(w << 16); }
__device__ __forceinline__ float b2f_hi(u32 w){ return __uint_as_float(w & 0xffff0000u); }
__device__ __forceinline__ float b2f(bf16 v){ return __bfloat162float(v); }
__device__ __forceinline__ bf16 f2b(float v){ return __float2bfloat16(v); }

__device__ __forceinline__ u32 f2bbits(float f){
  u32 x = __float_as_uint(f);
  return ((x + 0x7fffu + ((x >> 16) & 1u)) >> 16) & 0xffffu;  // RNE
}

__device__ __forceinline__ void unpack8(uint4 v, float* f){
  f[0]=b2f_lo(v.x); f[1]=b2f_hi(v.x);
  f[2]=b2f_lo(v.y); f[3]=b2f_hi(v.y);
  f[4]=b2f_lo(v.z); f[5]=b2f_hi(v.z);
  f[6]=b2f_lo(v.w); f[7]=b2f_hi(v.w);
}

union ABu { u32 u[4]; bf16x8 v; uint4 q; };

// XOR-swizzled xs index (stride 112 units per c8)
__device__ __forceinline__ int xsw(int c8, int px){
  return c8 * 112 + ((px & ~7) | ((px ^ c8) & 7));
}

// ---------------- K12 (v8): pointwise qkv (MFMA) + 3x3 depthwise + tokenize.
// SMALL TILE for inter-block pipe overlap: block = (b, yt 8-row band, xt 8-col strip),
// region 10x10 = 100 px (pad 112). LDS 29.6 KB -> 5 blocks/CU.
__global__ __launch_bounds__(256) void k12_fused(
    const float* __restrict__ x, const float* __restrict__ wq,
    const float* __restrict__ wdw, bf16* __restrict__ tok){
  __shared__ uint4 xs[8 * 112];              // 14.3 KB
  __shared__ unsigned short qs[112 * 68];    // 15.2 KB
  int t = threadIdx.x;
  int lane = t & 63, w = t >> 6;
  int r16 = lane & 15, g4 = lane >> 4;

  u32 n = blockIdx.x;
  u32 bid = (n & 7u) * 2048u + (n >> 3);     // XCD swizzle (16384 = 8*2048, bijective)
  u32 xt = bid & 31u, yt = (bid >> 5) & 31u, b = bid >> 10;
  int y0 = (int)yt * 8, x0 = (int)xt * 8;

  const float* xb = x + (size_t)b * 64 * HWSZ;

  // ---- stage x: 160 units = (c8, rr in [0,10), jh in {0,1}); unit = 4 ch x 10 cols
  if (t < 160){
    int u = t;
    int jh = u & 1, rr = (u >> 1) % 10, c8 = u / 20;
    int yy = y0 - 1 + rr;
    float va[4][10];
    if ((u32)yy < 256u){
      #pragma unroll
      for (int jc = 0; jc < 4; jc++){
        const float* p = xb + (size_t)(c8 * 8 + jh * 4 + jc) * HWSZ + ((size_t)yy << 8);
        float4 A  = *(const float4*)(p + x0);        // 16B-aligned (x0 % 8 == 0)
        float4 Bq = *(const float4*)(p + x0 + 4);
        va[jc][0] = (x0 > 0) ? p[x0 - 1] : 0.f;
        va[jc][1] = A.x;  va[jc][2] = A.y;  va[jc][3] = A.z;  va[jc][4] = A.w;
        va[jc][5] = Bq.x; va[jc][6] = Bq.y; va[jc][7] = Bq.z; va[jc][8] = Bq.w;
        va[jc][9] = (x0 + 8 < 256) ? p[x0 + 8] : 0.f;
      }
    } else {
      #pragma unroll
      for (int jc = 0; jc < 4; jc++)
        #pragma unroll
        for (int e = 0; e < 10; e++) va[jc][e] = 0.f;
    }
    #pragma unroll
    for (int e = 0; e < 10; e++){
      u32 w0 = f2bbits(va[0][e]) | (f2bbits(va[1][e]) << 16);
      u32 w1 = f2bbits(va[2][e]) | (f2bbits(va[3][e]) << 16);
      ((uint2*)&xs[xsw(c8, rr * 10 + e)])[jh] = make_uint2(w0, w1);
    }
  }
  if (t < 96){                                        // zero-pad px 100..111
    int c8 = t / 12, px = 100 + (t % 12);
    xs[xsw(c8, px)] = make_uint4(0u, 0u, 0u, 0u);
  }

  int cth = t & 63, rq = w;                           // dwconv: (ch, row-pair)
  u32 win = (yt >> 2) * 8u + (xt >> 2);

  for (int g = 0; g < 3; g++){
    __syncthreads();                                  // xs ready / qs free
    // ---- pointwise MFMA: wave w owns och-tile w (16 rows of 64), 7 n-tiles
    bf16x8 af[2];
    {
      int och = g * 64 + w * 16 + r16;
      #pragma unroll
      for (int kt = 0; kt < 2; kt++){
        const float* wr = wq + och * 64 + kt * 32 + g4 * 8;
        ABu pk;
        #pragma unroll
        for (int j = 0; j < 4; j++)
          pk.u[j] = f2bbits(wr[2 * j]) | (f2bbits(wr[2 * j + 1]) << 16);
        af[kt] = pk.v;
      }
    }
    #pragma unroll
    for (int nt = 0; nt < 7; nt++){
      f32x4 acc = (f32x4){0.f, 0.f, 0.f, 0.f};
      #pragma unroll
      for (int kt = 0; kt < 2; kt++){
        uint4 uq = xs[xsw(kt * 4 + g4, nt * 16 + r16)];
        acc = __builtin_amdgcn_mfma_f32_16x16x32_bf16(
            af[kt], *reinterpret_cast<bf16x8*>(&uq), acc, 0, 0, 0);
      }
      int px = nt * 16 + r16;
      u32 lo = f2bbits(acc[0]) | (f2bbits(acc[1]) << 16);
      u32 hi = f2bbits(acc[2]) | (f2bbits(acc[3]) << 16);
      *(uint2*)&qs[px * 68 + w * 16 + g4 * 4] = make_uint2(lo, hi);
    }
    __syncthreads();                                  // qs ready

    // ---- depthwise 3x3 + tokenized store: thread = (cth, rows rq*2, rq*2+1)
    const float* wg = wdw + ((size_t)g * 64 + cth) * 9;
    float d0=wg[0],d1=wg[1],d2=wg[2],d3=wg[3],d4=wg[4],d5=wg[5],d6=wg[6],d7=wg[7],d8=wg[8];
    float rbf[4][10];
    #define QLD(s, R) do{ _Pragma("unroll") for (int _cr = 0; _cr < 10; _cr++) \
      rbf[s][_cr] = __uint_as_float(((u32)qs[((R) * 10 + _cr) * 68 + cth]) << 16); }while(0)
    QLD(0, rq * 2 + 0);
    QLD(1, rq * 2 + 1);
    QLD(2, rq * 2 + 2);
    QLD(3, rq * 2 + 3);
    #undef QLD
    #pragma unroll
    for (int rr2 = 0; rr2 < 2; rr2++){
      int r = rq * 2 + rr2;
      int h = (int)(yt & 3u) * 2 + (r >> 2);
      bf16* op = tok + (((((size_t)g * 16 + b) * 8 + h) * 64 + win) * 8192)
               + (size_t)(r & 3) * 2048 + (size_t)((xt & 3u) * 8) * 64 + cth;
      #pragma unroll
      for (int co = 0; co < 8; co++){
        float o = rbf[rr2][co]    * d0 + rbf[rr2][co + 1]    * d1 + rbf[rr2][co + 2]    * d2
                + rbf[rr2 + 1][co]* d3 + rbf[rr2 + 1][co + 1]* d4 + rbf[rr2 + 1][co + 2]* d5
                + rbf[rr2 + 2][co]* d6 + rbf[rr2 + 2][co + 1]* d7 + rbf[rr2 + 2][co + 2]* d8;
        op[co * 64] = f2b(o);
      }
    }
  }
}

// ---------------- K3 (MFMA): sim partials over d-quarter -> sim4[part][b][h][64][64]
__global__ __launch_bounds__(256) void k3_sim(
    const bf16* __restrict__ tok, float* __restrict__ sim4){
  __shared__ short qs[64 * 72];
  __shared__ short ks[64 * 72];
  int t = threadIdx.x;
  int lane = t & 63, w = t >> 6;
  int r16 = lane & 15, g4 = lane >> 4;
  u32 bid = blockIdx.x;
  u32 part = bid & 3u, h = (bid >> 2) & 7u, b = bid >> 5;
  const bf16* qb = tok + ((size_t)(((0 * 16 + b) * 8 + h) * 64)) * 8192 + part * 2048;
  const bf16* kb = tok + ((size_t)(((1 * 16 + b) * 8 + h) * 64)) * 8192 + part * 2048;

  int stok = t >> 2, soct = t & 3;

  f32x4 acc[4];
  #pragma unroll
  for (int jt = 0; jt < 4; jt++) acc[jt] = (f32x4){0.f,0.f,0.f,0.f};

  for (int s = 0; s < 32; s++){
    int d0 = s * 64;
    __syncthreads();
    {
      uint4 q0 = *(const uint4*)(qb + (size_t)stok * 8192 + d0 + soct * 8);
      uint4 q1 = *(const uint4*)(qb + (size_t)stok * 8192 + d0 + soct * 8 + 32);
      uint4 k0 = *(const uint4*)(kb + (size_t)stok * 8192 + d0 + soct * 8);
      uint4 k1 = *(const uint4*)(kb + (size_t)stok * 8192 + d0 + soct * 8 + 32);
      *(uint4*)&qs[stok * 72 + soct * 8]      = q0;
      *(uint4*)&qs[stok * 72 + soct * 8 + 32] = q1;
      *(uint4*)&ks[stok * 72 + soct * 8]      = k0;
      *(uint4*)&ks[stok * 72 + soct * 8 + 32] = k1;
    }
    __syncthreads();
    #pragma unroll
    for (int kt = 0; kt < 2; kt++){
      bf16x8 a = *(const bf16x8*)&qs[(w * 16 + r16) * 72 + kt * 32 + g4 * 8];
      #pragma unroll
      for (int jt = 0; jt < 4; jt++){
        bf16x8 bb = *(const bf16x8*)&ks[(jt * 16 + r16) * 72 + kt * 32 + g4 * 8];
        acc[jt] = __builtin_amdgcn_mfma_f32_16x16x32_bf16(a, bb, acc[jt], 0, 0, 0);
      }
    }
  }

  float* sp = sim4 + ((((size_t)part * 16 + b) * 8 + h) * 64) * 64;
  #pragma unroll
  for (int jt = 0; jt < 4; jt++)
    #pragma unroll
    for (int r = 0; r < 4; r++)
      sp[(w * 16 + g4 * 4 + r) * 64 + jt * 16 + r16] = acc[jt][r];
}

// ---------------- K4: combine partials, scale, +pos_emb, softmax
__global__ __launch_bounds__(64) void k4_softmax(
    const float* __restrict__ sim4, const float* __restrict__ pos, float* __restrict__ attn){
  int j = threadIdx.x;
  u32 bid = blockIdx.x;
  u32 i = bid & 63u, h = (bid >> 6) & 7u, b = bid >> 9;
  size_t o = (((size_t)b * 8 + h) * 64 + i) * 64 + j;
  const size_t pstride = (size_t)16 * 8 * 64 * 64;
  float s = sim4[o] + sim4[o + pstride] + sim4[o + 2 * pstride] + sim4[o + 3 * pstride];
  s = s * 0.011048543456039806f + pos[(((size_t)h * 64) + i) * 64 + j];
  float m = s;
  #pragma unroll
  for (int off = 32; off; off >>= 1) m = fmaxf(m, __shfl_xor(m, off));
  float e = __expf(s - m);
  float sum = e;
  #pragma unroll
  for (int off = 32; off; off >>= 1) sum += __shfl_xor(sum, off);
  attn[o] = e / sum;
}

// ---------------- K5 (MFMA): otok[i,d] = sum_j attn[i,j] * V[j,d]
__global__ __launch_bounds__(256) void k5_av(
    const bf16* __restrict__ tok, const float* __restrict__ attn, bf16* __restrict__ otok){
  __shared__ short vt[4][64 * 72];
  int t = threadIdx.x;
  int lane = t & 63, w = t >> 6;
  int r16 = lane & 15, g4 = lane >> 4;
  u32 bid = blockIdx.x;
  u32 q = bid & 3u, h = (bid >> 2) & 7u, b = bid >> 5;
  const bf16* vb = tok + ((size_t)(((2 * 16 + b) * 8 + h) * 64)) * 8192;
  const float* ab = attn + (((size_t)b * 8 + h) * 64) * 64;
  bf16* ob = otok + (((size_t)b * 8 + h) * 64) * 8192;

  bf16x8 af[4][2];
  #pragma unroll
  for (int it = 0; it < 4; it++)
    #pragma unroll
    for (int kt = 0; kt < 2; kt++){
      const float* ar = ab + (it * 16 + r16) * 64 + kt * 32 + g4 * 8;
      ABu pk;
      #pragma unroll
      for (int j = 0; j < 4; j++)
        pk.u[j] = f2bbits(ar[2 * j]) | (f2bbits(ar[2 * j + 1]) << 16);
      af[it][kt] = pk.v;
    }

  short* vtw = vt[w];
  for (int s = 0; s < 8; s++){
    int d0 = (int)q * 2048 + s * 256 + w * 64;
    uint4 ld[8];
    const bf16* vp = vb + (size_t)lane * 8192 + d0;
    #pragma unroll
    for (int u = 0; u < 8; u++) ld[u] = *(const uint4*)(vp + u * 8);
    #pragma unroll
    for (int u = 0; u < 8; u++){
      const u32* wd = (const u32*)&ld[u];
      #pragma unroll
      for (int e = 0; e < 4; e++){
        int d = u * 8 + e * 2;
        vtw[d * 72 + lane]       = (short)(wd[e] & 0xffffu);
        vtw[(d + 1) * 72 + lane] = (short)(wd[e] >> 16);
      }
    }
    #pragma unroll
    for (int dt = 0; dt < 4; dt++){
      bf16x8 b0 = *(const bf16x8*)&vtw[(dt * 16 + r16) * 72 + 0 * 32 + g4 * 8];
      bf16x8 b1 = *(const bf16x8*)&vtw[(dt * 16 + r16) * 72 + 1 * 32 + g4 * 8];
      #pragma unroll
      for (int it = 0; it < 4; it++){
        f32x4 acc = (f32x4){0.f,0.f,0.f,0.f};
        acc = __builtin_amdgcn_mfma_f32_16x16x32_bf16(af[it][0], b0, acc, 0, 0, 0);
        acc = __builtin_amdgcn_mfma_f32_16x16x32_bf16(af[it][1], b1, acc, 0, 0, 0);
        #pragma unroll
        for (int r = 0; r < 4; r++)
          ob[(size_t)(it * 16 + g4 * 4 + r) * 8192 + d0 + dt * 16 + r16] = f2b(acc[r]);
      }
    }
  }
}

// ---------------- K6 (MFMA): out[b,64,HW] fp32 = Wp[64,64] x OT[64,HW] + bias
__global__ __launch_bounds__(256) void k6_mfma(
    const bf16* __restrict__ otok, const float* __restrict__ wp,
    const float* __restrict__ bp, float* __restrict__ out){
  __shared__ uint4 xs[1024];
  int t = threadIdx.x;
  int lane = t & 63, w = t >> 6;
  u32 pix0 = blockIdx.x * 128u;
  u32 b = pix0 >> 16, hw0 = pix0 & 65535u;
  int y = (int)(hw0 >> 8);
  int p0 = y & 31, h = p0 >> 2, prow = (p0 & 3) * 2048;
  int iy = (y >> 5) << 3;

  {
    int pix = t & 127, half = t >> 7;
    int xx = (int)(hw0 & 255u) + pix;
    int i = iy + (xx >> 5), p1 = xx & 31;
    const bf16* ip = otok + ((((size_t)b * 8 + h) * 64 + i)) * 8192 + prow + p1 * 64;
    #pragma unroll
    for (int g = 0; g < 4; g++){
      int c8 = half * 4 + g;
      xs[c8 * 128 + pix] = *(const uint4*)(ip + c8 * 8);
    }
  }

  int r16 = lane & 15, g4 = lane >> 4;
  bf16x8 af[2];
  int och = w * 16 + r16;
  #pragma unroll
  for (int kt = 0; kt < 2; kt++){
    const float* wr = wp + och * 64 + kt * 32 + g4 * 8;
    ABu pk;
    #pragma unroll
    for (int j = 0; j < 4; j++)
      pk.u[j] = f2bbits(wr[2 * j]) | (f2bbits(wr[2 * j + 1]) << 16);
    af[kt] = pk.v;
  }
  float bias[4];
  #pragma unroll
  for (int r = 0; r < 4; r++) bias[r] = bp[w * 16 + g4 * 4 + r];
  __syncthreads();

  f32x4 acc[8];
  #pragma unroll
  for (int pt = 0; pt < 8; pt++) acc[pt] = (f32x4){bias[0], bias[1], bias[2], bias[3]};

  #pragma unroll
  for (int pt = 0; pt < 8; pt++){
    uint4 u0 = xs[(0 * 4 + g4) * 128 + pt * 16 + r16];
    uint4 u1 = xs[(1 * 4 + g4) * 128 + pt * 16 + r16];
    bf16x8 b0 = *reinterpret_cast<bf16x8*>(&u0);
    bf16x8 b1 = *reinterpret_cast<bf16x8*>(&u1);
    acc[pt] = __builtin_amdgcn_mfma_f32_16x16x32_bf16(af[0], b0, acc[pt], 0, 0, 0);
    acc[pt] = __builtin_amdgcn_mfma_f32_16x16x32_bf16(af[1], b1, acc[pt], 0, 0, 0);
  }

  float* op = out + (size_t)b * 64 * HWSZ + hw0;
  int ochb = w * 16 + g4 * 4;
  #pragma unroll
  for (int pt = 0; pt < 8; pt++)
    #pragma unroll
    for (int r = 0; r < 4; r++)
      op[(size_t)(ochb + r) * HWSZ + pt * 16 + r16] = acc[pt][r];
}

extern "C" void kernel_launch(void* const* d_in, const int* in_sizes, int n_in,
                              void* d_out, int out_size, void* d_ws, size_t ws_size,
                              hipStream_t stream){
  const float* x   = (const float*)d_in[0];
  const float* wq  = (const float*)d_in[1];
  const float* wdw = (const float*)d_in[2];
  const float* wp  = (const float*)d_in[3];
  const float* bp  = (const float*)d_in[4];
  const float* pos = (const float*)d_in[5];
  float* out = (float*)d_out;
  (void)in_sizes; (void)n_in; (void)out_size; (void)ws_size;

  char* ws = (char*)d_ws;
  bf16*  tok  = (bf16*)(ws + 402653184u);
  bf16*  otok = (bf16*)ws;
  float* sim4 = (float*)(ws + 134217728u);
  float* attn = (float*)(ws + 142606336u);

  k12_fused<<<dim3(16384), dim3(256), 0, stream>>>(x, wq, wdw, tok);
  k3_sim<<<dim3(512),   dim3(256), 0, stream>>>(tok, sim4);
  k4_softmax<<<dim3(8192), dim3(64), 0, stream>>>(sim4, pos, attn);
  k5_av<<<dim3(512),  dim3(256), 0, stream>>>(tok, attn, otok);
  k6_mfma<<<dim3(8192), dim3(256), 0, stream>>>(otok, wp, bp, out);
}